// Round 7
// baseline (163.696 us; speedup 1.0000x reference)
//
#include <hip/hip_runtime.h>
#include <hip/hip_bf16.h>

// Problem: OptimAttn  B=32, SIZE=2048, OUT=2048 — ALL I/O float32.
// valued[b,i] = sum_j exp(q_i k_j - M) v_j / Z_b,  Z_b = sum_{i,j} exp(q_i k_j - M)
// M = max of 4 corner products of (qmin,qmax)x(kmin,kmax)  (exact global max).
// Matmuls: truncation-split bf16 MFMA (f32 = hi + lo; 3 MFMAs) -> ~2^-16 rel error.
// Round 7: k_act fused into k_attn the CHEAP way — only Spart (16 scalars/batch)
// crosses blocks via scoped atomics; T stays in registers; all 16 blocks/batch
// spin (co-resident: 512 blocks = exactly 2/CU) then write fc directly.
// No __threadfence/wbl2, no bulk atomic-RMW reads (R6's +10.7us mistake).

#define S 2048
#define BATCH 32

typedef __attribute__((ext_vector_type(8))) short short8;   // 8 x bf16 (MFMA A/B frag)
typedef __attribute__((ext_vector_type(4))) float f32x4;    // MFMA C/D frag
typedef __attribute__((ext_vector_type(2))) float f32x2;    // packed fp32

#if __has_builtin(__builtin_elementwise_fma)
__device__ __forceinline__ f32x2 pkfma(f32x2 a, f32x2 b, f32x2 c) {
  return __builtin_elementwise_fma(a, b, c);
}
#else
__device__ __forceinline__ f32x2 pkfma(f32x2 a, f32x2 b, f32x2 c) {
  f32x2 r; r.x = fmaf(a.x, b.x, c.x); r.y = fmaf(a.y, b.y, c.y); return r;
}
#endif

// Truncation-based f32 -> (hi,lo) bf16 split, ~4 VALU/elem.
__device__ __forceinline__ void cvt8t(const float* __restrict__ p, short8& hi, short8& lo) {
  const float4* p4 = (const float4*)p;
  float4 a = p4[0], b = p4[1];
  float v[8] = {a.x, a.y, a.z, a.w, b.x, b.y, b.z, b.w};
#pragma unroll
  for (int t = 0; t < 8; ++t) {
    union { float f; unsigned u; } x; x.f = v[t];
    hi[t] = (short)(x.u >> 16);
    union { unsigned u; float f; } h; h.u = x.u & 0xFFFF0000u;
    union { float f; unsigned u; } l; l.f = v[t] - h.f;
    lo[t] = (short)(l.u >> 16);
  }
}

// ---------------- K1: qkv partials = x @ W{q,k,v}.T over K-half ----------------
// grid: 768 = mi(3) x kh(2) x nblk(128).  wg=256: 4 waves x 256 K each.
// Block 0 also clears cnt[32] (visible to k_attn at kernel boundary).
__global__ __launch_bounds__(256) void k_qkv(
    const float* __restrict__ x,
    const float* __restrict__ Wq,
    const float* __restrict__ Wk,
    const float* __restrict__ Wv,
    float* __restrict__ qkvp,
    int* __restrict__ cnt) {
  int bid  = blockIdx.x;
  int tid  = threadIdx.x;
  if (bid == 0 && tid < BATCH) cnt[tid] = 0;
  int mi   = bid >> 8;          // 0..2
  int kh   = (bid >> 7) & 1;    // K half
  int nblk = bid & 127;
  const float* W = (mi == 0) ? Wq : (mi == 1) ? Wk : Wv;
  float* out = qkvp + (size_t)kh * (3 * BATCH * S) + (size_t)mi * (BATCH * S);

  int wave = tid >> 6;
  int lane = tid & 63;
  int lr   = lane & 15;
  int quad = lane >> 4;

  f32x4 acc0 = {0.f, 0.f, 0.f, 0.f};
  f32x4 acc1 = {0.f, 0.f, 0.f, 0.f};
  const float* wrow = W + (size_t)(nblk * 16 + lr) * S;
  const float* xr0  = x + (size_t)lr * S;
  const float* xr1  = x + (size_t)(lr + 16) * S;
  int kbase = kh * 1024 + wave * 256 + quad * 8;

#pragma unroll 2
  for (int ks = 0; ks < 8; ++ks) {
    int k0 = kbase + ks * 32;
    short8 bhi, blo, a0h, a0l, a1h, a1l;
    cvt8t(wrow + k0, bhi, blo);
    cvt8t(xr0 + k0, a0h, a0l);
    cvt8t(xr1 + k0, a1h, a1l);
    acc0 = __builtin_amdgcn_mfma_f32_16x16x32_bf16(a0h, bhi, acc0, 0, 0, 0);
    acc0 = __builtin_amdgcn_mfma_f32_16x16x32_bf16(a0l, bhi, acc0, 0, 0, 0);
    acc0 = __builtin_amdgcn_mfma_f32_16x16x32_bf16(a0h, blo, acc0, 0, 0, 0);
    acc1 = __builtin_amdgcn_mfma_f32_16x16x32_bf16(a1h, bhi, acc1, 0, 0, 0);
    acc1 = __builtin_amdgcn_mfma_f32_16x16x32_bf16(a1l, bhi, acc1, 0, 0, 0);
    acc1 = __builtin_amdgcn_mfma_f32_16x16x32_bf16(a1h, blo, acc1, 0, 0, 0);
  }

  __shared__ float red[4][64][8];
#pragma unroll
  for (int r = 0; r < 4; ++r) {
    red[wave][lane][r]     = acc0[r];
    red[wave][lane][4 + r] = acc1[r];
  }
  __syncthreads();
  if (tid < 64) {
    int lq = tid >> 4, lc = tid & 15;
    int n = nblk * 16 + lc;
#pragma unroll
    for (int r = 0; r < 8; ++r) {
      float s = red[0][tid][r] + red[1][tid][r] + red[2][tid][r] + red[3][tid][r];
      int m = (r < 4) ? (lq * 4 + r) : (16 + lq * 4 + (r - 4));
      out[m * S + n] = s;
    }
  }
}

// ---------------- K2: attention + fused activation (scalar-only cross-block sync) ----
// grid: 512 = 32 batches * 16 i-blocks of 128.  wg=512: lane owns i and i+64 (packed),
// wave = j-chunk of 256.  Exactly 2 blocks/CU (LDS 19KB, low VGPR) -> all co-resident,
// so spinning on cnt[b] is deadlock-free.  T never leaves registers.
__global__ __launch_bounds__(512) void k_attn(
    const float* __restrict__ qkvp, float* __restrict__ Spart,
    int* __restrict__ cnt, const float* __restrict__ p2, float* __restrict__ fc) {
  int b    = blockIdx.x >> 4;
  int iblk = blockIdx.x & 15;
  const float* qA = qkvp + (size_t)b * S;
  const float* kA = qA + BATCH * S;
  const float* vA = qA + 2 * BATCH * S;
  const float* qB = qA + 3 * BATCH * S;
  const float* kB = kA + 3 * BATCH * S;
  const float* vB = vA + 3 * BATCH * S;

  __shared__ __align__(16) float2 kv[S];
  __shared__ float qsh[128];
  __shared__ float redmx[8][4];
  __shared__ f32x2 redT[512];
  __shared__ float redS[512];
  __shared__ float Msh;
  __shared__ float Zsh;

  int tid = threadIdx.x;
  float qmx = -1e30f, qmn = 1e30f, kmx = -1e30f, kmn = 1e30f;
  for (int idx = tid; idx < S; idx += 512) {
    float kk = kA[idx] + kB[idx];
    float vv = vA[idx] + vB[idx];
    float qq = qA[idx] + qB[idx];
    kv[idx] = make_float2(kk, vv);
    if ((idx >> 7) == iblk) qsh[idx & 127] = qq;
    qmx = fmaxf(qmx, qq); qmn = fminf(qmn, qq);
    kmx = fmaxf(kmx, kk); kmn = fminf(kmn, kk);
  }
  for (int off = 32; off; off >>= 1) {
    qmx = fmaxf(qmx, __shfl_xor(qmx, off));
    qmn = fminf(qmn, __shfl_xor(qmn, off));
    kmx = fmaxf(kmx, __shfl_xor(kmx, off));
    kmn = fminf(kmn, __shfl_xor(kmn, off));
  }
  int wave = tid >> 6, lane = tid & 63;
  if (lane == 0) {
    redmx[wave][0] = qmx; redmx[wave][1] = qmn;
    redmx[wave][2] = kmx; redmx[wave][3] = kmn;
  }
  __syncthreads();
  if (tid == 0) {
    float a = redmx[0][0], bn = redmx[0][1], c = redmx[0][2], d = redmx[0][3];
    for (int w = 1; w < 8; ++w) {
      a = fmaxf(a, redmx[w][0]); bn = fminf(bn, redmx[w][1]);
      c = fmaxf(c, redmx[w][2]); d = fminf(d, redmx[w][3]);
    }
    Msh = fmaxf(fmaxf(a * c, a * d), fmaxf(bn * c, bn * d));
  }
  __syncthreads();
  float M = Msh;

  const float LOG2E = 1.4426950408889634f;
  f32x2 aa = {qsh[lane] * LOG2E, qsh[lane + 64] * LOG2E};
  float ccs = -M * LOG2E;
  f32x2 cc = {ccs, ccs};
  f32x2 Sp = {0.f, 0.f}, Sq = {0.f, 0.f};
  f32x2 Tp = {0.f, 0.f}, Tq = {0.f, 0.f};
  int j0 = wave * 256;
#pragma unroll 4
  for (int j = j0; j < j0 + 256; j += 2) {
    float4 p = *(const float4*)&kv[j];   // (k0,v0,k1,v1) wave-uniform -> broadcast
    f32x2 kk0 = {p.x, p.x}, vv0 = {p.y, p.y};
    f32x2 kk1 = {p.z, p.z}, vv1 = {p.w, p.w};
    f32x2 a0 = pkfma(aa, kk0, cc);
    f32x2 a1 = pkfma(aa, kk1, cc);
    f32x2 e0 = {__builtin_amdgcn_exp2f(a0.x), __builtin_amdgcn_exp2f(a0.y)};
    f32x2 e1 = {__builtin_amdgcn_exp2f(a1.x), __builtin_amdgcn_exp2f(a1.y)};
    Sp += e0;
    Sq += e1;
    Tp = pkfma(e0, vv0, Tp);
    Tq = pkfma(e1, vv1, Tq);
  }
  redT[tid] = Tp + Tq;
  redS[tid] = Sp.x + Sp.y + Sq.x + Sq.y;
  __syncthreads();

  float Tf = 0.f;            // T[b, iblk*128 + tid] for tid<128 — stays in register
  if (tid < 128) {
    int l = tid & 63, hi = tid >> 6;
#pragma unroll
    for (int w = 0; w < 8; ++w) {
      f32x2 t = redT[w * 64 + l];
      Tf += hi ? t.y : t.x;
    }
  }
  if (tid < 64) {
    float Sf = 0.f;
#pragma unroll
    for (int w = 0; w < 8; ++w) Sf += redS[w * 64 + tid];
    for (int off = 32; off; off >>= 1) Sf += __shfl_xor(Sf, off);
    if (tid == 0) {
      // publish this block's partial sum (write-through to coherent point),
      // then release-bump the batch counter.
      __hip_atomic_store(&Spart[b * 16 + iblk], Sf,
                         __ATOMIC_RELAXED, __HIP_MEMORY_SCOPE_AGENT);
      __hip_atomic_fetch_add(&cnt[b], 1, __ATOMIC_RELEASE, __HIP_MEMORY_SCOPE_AGENT);
    }
  }

  // ---- wait for all 16 blocks of this batch (co-resident -> safe), form Z ----
  if (tid == 0) {
    while (__hip_atomic_load(&cnt[b], __ATOMIC_ACQUIRE, __HIP_MEMORY_SCOPE_AGENT) < 16)
      __builtin_amdgcn_s_sleep(1);
    float z = 0.f;
#pragma unroll
    for (int t = 0; t < 16; ++t)
      z += __hip_atomic_load(&Spart[b * 16 + t], __ATOMIC_RELAXED,
                             __HIP_MEMORY_SCOPE_AGENT);
    Zsh = z;
  }
  __syncthreads();

  if (tid < 128) {
    float Zinv = __builtin_amdgcn_rcpf(Zsh);
    float p[5];
    float mx = -1e30f;
#pragma unroll
    for (int t = 0; t < 5; ++t) { p[t] = p2[t]; mx = fmaxf(mx, p[t]); }
    float se = 0.f;
#pragma unroll
    for (int t = 0; t < 5; ++t) { p[t] = __builtin_amdgcn_exp2f((p[t] - mx) * LOG2E); se += p[t]; }
    float inv = 1.f / se;
    float val = Tf * Zinv;
    float sig = __builtin_amdgcn_rcpf(1.f + __builtin_amdgcn_exp2f(-val * LOG2E));
    float sn  = __builtin_amdgcn_sinf(val * 0.15915494309189535f);  // revolutions
    fc[b * S + iblk * 128 + tid] =
        sig * val * (p[0] * inv) + sn * (p[1] * inv) + val * (p[2] * inv);
  }
}

// ---------------- K3: y partials = fc @ Wfc2.T over K-quarter (no bias) ----------------
// grid: 512 = kq(4) x nblk(128).  wg=256: 4 waves x 128 K each.
__global__ __launch_bounds__(256) void k_fc(
    const float* __restrict__ fc,
    const float* __restrict__ W,
    float* __restrict__ yp) {
  int bid  = blockIdx.x;
  int kq   = bid >> 7;          // 0..3
  int nblk = bid & 127;
  int tid  = threadIdx.x;
  int wave = tid >> 6;
  int lane = tid & 63;
  int lr   = lane & 15;
  int quad = lane >> 4;

  f32x4 acc0 = {0.f, 0.f, 0.f, 0.f};
  f32x4 acc1 = {0.f, 0.f, 0.f, 0.f};
  const float* wrow = W + (size_t)(nblk * 16 + lr) * S;
  const float* xr0  = fc + (size_t)lr * S;
  const float* xr1  = fc + (size_t)(lr + 16) * S;
  int kbase = kq * 512 + wave * 128 + quad * 8;

#pragma unroll
  for (int ks = 0; ks < 4; ++ks) {
    int k0 = kbase + ks * 32;
    short8 bhi, blo, a0h, a0l, a1h, a1l;
    cvt8t(wrow + k0, bhi, blo);
    cvt8t(xr0 + k0, a0h, a0l);
    cvt8t(xr1 + k0, a1h, a1l);
    acc0 = __builtin_amdgcn_mfma_f32_16x16x32_bf16(a0h, bhi, acc0, 0, 0, 0);
    acc0 = __builtin_amdgcn_mfma_f32_16x16x32_bf16(a0l, bhi, acc0, 0, 0, 0);
    acc0 = __builtin_amdgcn_mfma_f32_16x16x32_bf16(a0h, blo, acc0, 0, 0, 0);
    acc1 = __builtin_amdgcn_mfma_f32_16x16x32_bf16(a1h, bhi, acc1, 0, 0, 0);
    acc1 = __builtin_amdgcn_mfma_f32_16x16x32_bf16(a1l, bhi, acc1, 0, 0, 0);
    acc1 = __builtin_amdgcn_mfma_f32_16x16x32_bf16(a1h, blo, acc1, 0, 0, 0);
  }

  __shared__ float red[4][64][8];
#pragma unroll
  for (int r = 0; r < 4; ++r) {
    red[wave][lane][r]     = acc0[r];
    red[wave][lane][4 + r] = acc1[r];
  }
  __syncthreads();
  if (tid < 64) {
    int lq = tid >> 4, lc = tid & 15;
    int n = nblk * 16 + lc;
#pragma unroll
    for (int r = 0; r < 8; ++r) {
      float s = red[0][tid][r] + red[1][tid][r] + red[2][tid][r] + red[3][tid][r];
      int m = (r < 4) ? (lq * 4 + r) : (16 + lq * 4 + (r - 4));
      yp[(size_t)kq * BATCH * S + m * S + n] = s;
    }
  }
}

// ---------------- K4: layernorm(y0+y1+y2+y3+bias) -> fp32 output ----------------
__global__ __launch_bounds__(256) void k_ln(
    const float* __restrict__ yp, const float* __restrict__ bias,
    const float* __restrict__ g, const float* __restrict__ bb,
    float* __restrict__ out) {
  int b = blockIdx.x;
  const float* r0 = yp + (size_t)b * S;
  const float* r1 = r0 + BATCH * S;
  const float* r2 = r1 + BATCH * S;
  const float* r3 = r2 + BATCH * S;
  float t8[8];
  float s = 0.f, s2 = 0.f;
#pragma unroll
  for (int it = 0; it < 8; ++it) {
    int i = threadIdx.x + it * 256;
    float t = (r0[i] + r1[i]) + (r2[i] + r3[i]) + bias[i];
    t8[it] = t;
    s += t; s2 += t * t;
  }
  for (int off = 32; off; off >>= 1) {
    s  += __shfl_xor(s, off);
    s2 += __shfl_xor(s2, off);
  }
  __shared__ float rs[4], rs2[4];
  __shared__ float mu_s, r_s;
  int wave = threadIdx.x >> 6, lane = threadIdx.x & 63;
  if (lane == 0) { rs[wave] = s; rs2[wave] = s2; }
  __syncthreads();
  if (threadIdx.x == 0) {
    float S1 = rs[0] + rs[1] + rs[2] + rs[3];
    float S2 = rs2[0] + rs2[1] + rs2[2] + rs2[3];
    float mu = S1 / (float)S;
    float var = S2 / (float)S - mu * mu;
    mu_s = mu;
    r_s = rsqrtf(var + 1e-5f);
  }
  __syncthreads();
  float mu = mu_s, r = r_s;
#pragma unroll
  for (int it = 0; it < 8; ++it) {
    int i = threadIdx.x + it * 256;
    out[b * S + i] = (t8[it] - mu) * r * g[i] + bb[i];
  }
}

extern "C" void kernel_launch(void* const* d_in, const int* in_sizes, int n_in,
                              void* d_out, int out_size, void* d_ws, size_t ws_size,
                              hipStream_t stream) {
  (void)in_sizes; (void)n_in; (void)out_size; (void)ws_size;
  const float* x    = (const float*)d_in[0];
  const float* Wq   = (const float*)d_in[1];
  const float* Wk   = (const float*)d_in[2];
  const float* Wv   = (const float*)d_in[3];
  const float* p2   = (const float*)d_in[4];
  const float* Wfc2 = (const float*)d_in[5];
  const float* bfc2 = (const float*)d_in[6];
  const float* g2   = (const float*)d_in[7];
  const float* b2   = (const float*)d_in[8];
  float* out = (float*)d_out;

  float* qkvp  = (float*)d_ws;                    // 2 * 3*32*2048 f32
  float* Spart = qkvp + 2 * 3 * BATCH * S;        // 32*16 f32
  int*   cnt   = (int*)(Spart + BATCH * 16);      // 32 i32
  float* fc    = (float*)(cnt + BATCH);           // 32*2048 f32
  float* yp    = fc + BATCH * S;                  // 4 * 32*2048 f32

  k_qkv<<<768, 256, 0, stream>>>(x, Wq, Wk, Wv, qkvp, cnt);
  k_attn<<<512, 512, 0, stream>>>(qkvp, Spart, cnt, p2, fc);
  k_fc<<<512, 256, 0, stream>>>(fc, Wfc2, yp);
  k_ln<<<32, 256, 0, stream>>>(yp, bfc2, g2, b2, out);
}

// Round 8
// 152.677 us; speedup vs baseline: 1.0722x; 1.0722x over previous
//
#include <hip/hip_runtime.h>
#include <hip/hip_bf16.h>

// Problem: OptimAttn  B=32, SIZE=2048, OUT=2048 — ALL I/O float32.
// valued[b,i] = sum_j exp(q_i k_j - M) v_j / Z_b,  Z_b = sum_{i,j} exp(q_i k_j - M)
// M = max of 4 corner products of (qmin,qmax)x(kmin,kmax)  (exact global max).
// Matmuls: truncation-split bf16 MFMA (f32 = hi + lo; 3 MFMAs) -> ~2^-16 rel error.
// Round 8: REVERT to R5 structure (best, 150.7us). In-kernel cross-block sync is
// strictly worse than a kernel-boundary gap on this problem (R6 +10.7, R7 +13).
// Micro-opts: k_act writes bf16 hi/lo split directly -> k_fc skips A cvt8t.

#define S 2048
#define BATCH 32

typedef __attribute__((ext_vector_type(8))) short short8;   // 8 x bf16 (MFMA A/B frag)
typedef __attribute__((ext_vector_type(4))) float f32x4;    // MFMA C/D frag
typedef __attribute__((ext_vector_type(2))) float f32x2;    // packed fp32

#if __has_builtin(__builtin_elementwise_fma)
__device__ __forceinline__ f32x2 pkfma(f32x2 a, f32x2 b, f32x2 c) {
  return __builtin_elementwise_fma(a, b, c);
}
#else
__device__ __forceinline__ f32x2 pkfma(f32x2 a, f32x2 b, f32x2 c) {
  f32x2 r; r.x = fmaf(a.x, b.x, c.x); r.y = fmaf(a.y, b.y, c.y); return r;
}
#endif

// Truncation-based f32 -> (hi,lo) bf16 split, ~4 VALU/elem.
__device__ __forceinline__ void cvt8t(const float* __restrict__ p, short8& hi, short8& lo) {
  const float4* p4 = (const float4*)p;
  float4 a = p4[0], b = p4[1];
  float v[8] = {a.x, a.y, a.z, a.w, b.x, b.y, b.z, b.w};
#pragma unroll
  for (int t = 0; t < 8; ++t) {
    union { float f; unsigned u; } x; x.f = v[t];
    hi[t] = (short)(x.u >> 16);
    union { unsigned u; float f; } h; h.u = x.u & 0xFFFF0000u;
    union { float f; unsigned u; } l; l.f = v[t] - h.f;
    lo[t] = (short)(l.u >> 16);
  }
}

// ---------------- K1: qkv partials = x @ W{q,k,v}.T over K-half ----------------
// grid: 768 = mi(3) x kh(2) x nblk(128).  wg=256: 4 waves x 256 K each.
__global__ __launch_bounds__(256) void k_qkv(
    const float* __restrict__ x,
    const float* __restrict__ Wq,
    const float* __restrict__ Wk,
    const float* __restrict__ Wv,
    float* __restrict__ qkvp) {
  int bid  = blockIdx.x;
  int tid  = threadIdx.x;
  int mi   = bid >> 8;          // 0..2
  int kh   = (bid >> 7) & 1;    // K half
  int nblk = bid & 127;
  const float* W = (mi == 0) ? Wq : (mi == 1) ? Wk : Wv;
  float* out = qkvp + (size_t)kh * (3 * BATCH * S) + (size_t)mi * (BATCH * S);

  int wave = tid >> 6;
  int lane = tid & 63;
  int lr   = lane & 15;
  int quad = lane >> 4;

  f32x4 acc0 = {0.f, 0.f, 0.f, 0.f};
  f32x4 acc1 = {0.f, 0.f, 0.f, 0.f};
  const float* wrow = W + (size_t)(nblk * 16 + lr) * S;
  const float* xr0  = x + (size_t)lr * S;
  const float* xr1  = x + (size_t)(lr + 16) * S;
  int kbase = kh * 1024 + wave * 256 + quad * 8;

#pragma unroll 2
  for (int ks = 0; ks < 8; ++ks) {
    int k0 = kbase + ks * 32;
    short8 bhi, blo, a0h, a0l, a1h, a1l;
    cvt8t(wrow + k0, bhi, blo);
    cvt8t(xr0 + k0, a0h, a0l);
    cvt8t(xr1 + k0, a1h, a1l);
    acc0 = __builtin_amdgcn_mfma_f32_16x16x32_bf16(a0h, bhi, acc0, 0, 0, 0);
    acc0 = __builtin_amdgcn_mfma_f32_16x16x32_bf16(a0l, bhi, acc0, 0, 0, 0);
    acc0 = __builtin_amdgcn_mfma_f32_16x16x32_bf16(a0h, blo, acc0, 0, 0, 0);
    acc1 = __builtin_amdgcn_mfma_f32_16x16x32_bf16(a1h, bhi, acc1, 0, 0, 0);
    acc1 = __builtin_amdgcn_mfma_f32_16x16x32_bf16(a1l, bhi, acc1, 0, 0, 0);
    acc1 = __builtin_amdgcn_mfma_f32_16x16x32_bf16(a1h, blo, acc1, 0, 0, 0);
  }

  __shared__ float red[4][64][8];
#pragma unroll
  for (int r = 0; r < 4; ++r) {
    red[wave][lane][r]     = acc0[r];
    red[wave][lane][4 + r] = acc1[r];
  }
  __syncthreads();
  if (tid < 64) {
    int lq = tid >> 4, lc = tid & 15;
    int n = nblk * 16 + lc;
#pragma unroll
    for (int r = 0; r < 8; ++r) {
      float s = red[0][tid][r] + red[1][tid][r] + red[2][tid][r] + red[3][tid][r];
      int m = (r < 4) ? (lq * 4 + r) : (16 + lq * 4 + (r - 4));
      out[m * S + n] = s;
    }
  }
}

// ---------------- K2: attention numerator T[b,i] and partial sums Spart ----------------
// grid: 512 = 32 batches * 16 i-blocks of 128.  wg=512: lane owns i and i+64 (packed),
// wave = j-chunk of 256.
__global__ __launch_bounds__(512) void k_attn(
    const float* __restrict__ qkvp, float* __restrict__ Tout, float* __restrict__ Spart) {
  int b    = blockIdx.x >> 4;
  int iblk = blockIdx.x & 15;
  const float* qA = qkvp + (size_t)b * S;
  const float* kA = qA + BATCH * S;
  const float* vA = qA + 2 * BATCH * S;
  const float* qB = qA + 3 * BATCH * S;
  const float* kB = kA + 3 * BATCH * S;
  const float* vB = vA + 3 * BATCH * S;

  __shared__ __align__(16) float2 kv[S];
  __shared__ float qsh[128];
  __shared__ float redmx[8][4];
  __shared__ f32x2 redT[512];
  __shared__ float redS[512];
  __shared__ float Msh;

  int tid = threadIdx.x;
  float qmx = -1e30f, qmn = 1e30f, kmx = -1e30f, kmn = 1e30f;
  for (int idx = tid; idx < S; idx += 512) {
    float kk = kA[idx] + kB[idx];
    float vv = vA[idx] + vB[idx];
    float qq = qA[idx] + qB[idx];
    kv[idx] = make_float2(kk, vv);
    if ((idx >> 7) == iblk) qsh[idx & 127] = qq;
    qmx = fmaxf(qmx, qq); qmn = fminf(qmn, qq);
    kmx = fmaxf(kmx, kk); kmn = fminf(kmn, kk);
  }
  for (int off = 32; off; off >>= 1) {
    qmx = fmaxf(qmx, __shfl_xor(qmx, off));
    qmn = fminf(qmn, __shfl_xor(qmn, off));
    kmx = fmaxf(kmx, __shfl_xor(kmx, off));
    kmn = fminf(kmn, __shfl_xor(kmn, off));
  }
  int wave = tid >> 6, lane = tid & 63;
  if (lane == 0) {
    redmx[wave][0] = qmx; redmx[wave][1] = qmn;
    redmx[wave][2] = kmx; redmx[wave][3] = kmn;
  }
  __syncthreads();
  if (tid == 0) {
    float a = redmx[0][0], bn = redmx[0][1], c = redmx[0][2], d = redmx[0][3];
    for (int w = 1; w < 8; ++w) {
      a = fmaxf(a, redmx[w][0]); bn = fminf(bn, redmx[w][1]);
      c = fmaxf(c, redmx[w][2]); d = fminf(d, redmx[w][3]);
    }
    Msh = fmaxf(fmaxf(a * c, a * d), fmaxf(bn * c, bn * d));
  }
  __syncthreads();
  float M = Msh;

  const float LOG2E = 1.4426950408889634f;
  f32x2 aa = {qsh[lane] * LOG2E, qsh[lane + 64] * LOG2E};
  float ccs = -M * LOG2E;
  f32x2 cc = {ccs, ccs};
  f32x2 Sp = {0.f, 0.f}, Sq = {0.f, 0.f};
  f32x2 Tp = {0.f, 0.f}, Tq = {0.f, 0.f};
  int j0 = wave * 256;
#pragma unroll 4
  for (int j = j0; j < j0 + 256; j += 2) {
    float4 p = *(const float4*)&kv[j];   // (k0,v0,k1,v1) wave-uniform -> broadcast
    f32x2 kk0 = {p.x, p.x}, vv0 = {p.y, p.y};
    f32x2 kk1 = {p.z, p.z}, vv1 = {p.w, p.w};
    f32x2 a0 = pkfma(aa, kk0, cc);
    f32x2 a1 = pkfma(aa, kk1, cc);
    f32x2 e0 = {__builtin_amdgcn_exp2f(a0.x), __builtin_amdgcn_exp2f(a0.y)};
    f32x2 e1 = {__builtin_amdgcn_exp2f(a1.x), __builtin_amdgcn_exp2f(a1.y)};
    Sp += e0;
    Sq += e1;
    Tp = pkfma(e0, vv0, Tp);
    Tq = pkfma(e1, vv1, Tq);
  }
  redT[tid] = Tp + Tq;
  redS[tid] = Sp.x + Sp.y + Sq.x + Sq.y;
  __syncthreads();
  if (tid < 128) {
    int l = tid & 63, hi = tid >> 6;
    float Tf = 0.f;
#pragma unroll
    for (int w = 0; w < 8; ++w) {
      f32x2 t = redT[w * 64 + l];
      Tf += hi ? t.y : t.x;
    }
    Tout[b * S + iblk * 128 + tid] = Tf;
  }
  if (tid < 64) {
    float Sf = 0.f;
#pragma unroll
    for (int w = 0; w < 8; ++w) Sf += redS[w * 64 + tid];
    for (int off = 32; off; off >>= 1) Sf += __shfl_xor(Sf, off);
    if (tid == 0) Spart[b * 16 + iblk] = Sf;
  }
}

// ---------------- K2b: fc = activation(T/Z), written as bf16 hi/lo split ----------------
__global__ __launch_bounds__(256) void k_act(
    const float* __restrict__ Tin, const float* __restrict__ Spart,
    const float* __restrict__ p2,
    unsigned short* __restrict__ fchi, unsigned short* __restrict__ fclo) {
  int tid = threadIdx.x;
  int gid = blockIdx.x * 256 + tid;   // 0..65535
  int b = gid >> 11;                  // uniform per block (2048 per b, 8 blocks/b)
  __shared__ float Zsh;
  if (tid < 64) {
    float zv = (tid < 16) ? Spart[b * 16 + tid] : 0.f;
    for (int off = 32; off; off >>= 1) zv += __shfl_xor(zv, off);
    if (tid == 0) Zsh = zv;
  }
  __syncthreads();
  float Z = Zsh;

  const float LOG2E = 1.4426950408889634f;
  float p[5];
  float mx = -1e30f;
#pragma unroll
  for (int t = 0; t < 5; ++t) { p[t] = p2[t]; mx = fmaxf(mx, p[t]); }
  float se = 0.f;
#pragma unroll
  for (int t = 0; t < 5; ++t) { p[t] = __builtin_amdgcn_exp2f((p[t] - mx) * LOG2E); se += p[t]; }
  float inv = 1.f / se;
  float val = Tin[gid] / Z;
  float sig = __builtin_amdgcn_rcpf(1.f + __builtin_amdgcn_exp2f(-val * LOG2E));
  float sn  = __builtin_amdgcn_sinf(val * 0.15915494309189535f);  // v_sin takes revolutions
  float fcv = sig * val * (p[0] * inv) + sn * (p[1] * inv) + val * (p[2] * inv);
  // truncation split (same numerics as cvt8t)
  union { float f; unsigned u; } xx; xx.f = fcv;
  unsigned short h = (unsigned short)(xx.u >> 16);
  union { unsigned u; float f; } hh; hh.u = xx.u & 0xFFFF0000u;
  union { float f; unsigned u; } ll; ll.f = fcv - hh.f;
  fchi[gid] = h;
  fclo[gid] = (unsigned short)(ll.u >> 16);
}

// ---------------- K3: y partials = fc @ Wfc2.T over K-quarter (no bias) ----------------
// grid: 512 = kq(4) x nblk(128).  wg=256: 4 waves x 128 K each.
// A-fragments come pre-split from k_act (direct short8 loads, no cvt).
__global__ __launch_bounds__(256) void k_fc(
    const unsigned short* __restrict__ fchi,
    const unsigned short* __restrict__ fclo,
    const float* __restrict__ W,
    float* __restrict__ yp) {
  int bid  = blockIdx.x;
  int kq   = bid >> 7;          // 0..3
  int nblk = bid & 127;
  int tid  = threadIdx.x;
  int wave = tid >> 6;
  int lane = tid & 63;
  int lr   = lane & 15;
  int quad = lane >> 4;

  f32x4 acc0 = {0.f, 0.f, 0.f, 0.f};
  f32x4 acc1 = {0.f, 0.f, 0.f, 0.f};
  const float* wrow = W + (size_t)(nblk * 16 + lr) * S;
  const unsigned short* xh0 = fchi + (size_t)lr * S;
  const unsigned short* xl0 = fclo + (size_t)lr * S;
  const unsigned short* xh1 = fchi + (size_t)(lr + 16) * S;
  const unsigned short* xl1 = fclo + (size_t)(lr + 16) * S;
  int kbase = kq * 512 + wave * 128 + quad * 8;

#pragma unroll
  for (int ks = 0; ks < 4; ++ks) {
    int k0 = kbase + ks * 32;
    short8 bhi, blo;
    cvt8t(wrow + k0, bhi, blo);
    short8 a0h = *(const short8*)(xh0 + k0);
    short8 a0l = *(const short8*)(xl0 + k0);
    short8 a1h = *(const short8*)(xh1 + k0);
    short8 a1l = *(const short8*)(xl1 + k0);
    acc0 = __builtin_amdgcn_mfma_f32_16x16x32_bf16(a0h, bhi, acc0, 0, 0, 0);
    acc0 = __builtin_amdgcn_mfma_f32_16x16x32_bf16(a0l, bhi, acc0, 0, 0, 0);
    acc0 = __builtin_amdgcn_mfma_f32_16x16x32_bf16(a0h, blo, acc0, 0, 0, 0);
    acc1 = __builtin_amdgcn_mfma_f32_16x16x32_bf16(a1h, bhi, acc1, 0, 0, 0);
    acc1 = __builtin_amdgcn_mfma_f32_16x16x32_bf16(a1l, bhi, acc1, 0, 0, 0);
    acc1 = __builtin_amdgcn_mfma_f32_16x16x32_bf16(a1h, blo, acc1, 0, 0, 0);
  }

  __shared__ float red[4][64][8];
#pragma unroll
  for (int r = 0; r < 4; ++r) {
    red[wave][lane][r]     = acc0[r];
    red[wave][lane][4 + r] = acc1[r];
  }
  __syncthreads();
  if (tid < 64) {
    int lq = tid >> 4, lc = tid & 15;
    int n = nblk * 16 + lc;
#pragma unroll
    for (int r = 0; r < 8; ++r) {
      float s = red[0][tid][r] + red[1][tid][r] + red[2][tid][r] + red[3][tid][r];
      int m = (r < 4) ? (lq * 4 + r) : (16 + lq * 4 + (r - 4));
      yp[(size_t)kq * BATCH * S + m * S + n] = s;
    }
  }
}

// ---------------- K4: layernorm(y0+y1+y2+y3+bias) -> fp32 output ----------------
__global__ __launch_bounds__(256) void k_ln(
    const float* __restrict__ yp, const float* __restrict__ bias,
    const float* __restrict__ g, const float* __restrict__ bb,
    float* __restrict__ out) {
  int b = blockIdx.x;
  const float* r0 = yp + (size_t)b * S;
  const float* r1 = r0 + BATCH * S;
  const float* r2 = r1 + BATCH * S;
  const float* r3 = r2 + BATCH * S;
  float t8[8];
  float s = 0.f, s2 = 0.f;
#pragma unroll
  for (int it = 0; it < 8; ++it) {
    int i = threadIdx.x + it * 256;
    float t = (r0[i] + r1[i]) + (r2[i] + r3[i]) + bias[i];
    t8[it] = t;
    s += t; s2 += t * t;
  }
  for (int off = 32; off; off >>= 1) {
    s  += __shfl_xor(s, off);
    s2 += __shfl_xor(s2, off);
  }
  __shared__ float rs[4], rs2[4];
  __shared__ float mu_s, r_s;
  int wave = threadIdx.x >> 6, lane = threadIdx.x & 63;
  if (lane == 0) { rs[wave] = s; rs2[wave] = s2; }
  __syncthreads();
  if (threadIdx.x == 0) {
    float S1 = rs[0] + rs[1] + rs[2] + rs[3];
    float S2 = rs2[0] + rs2[1] + rs2[2] + rs2[3];
    float mu = S1 / (float)S;
    float var = S2 / (float)S - mu * mu;
    mu_s = mu;
    r_s = rsqrtf(var + 1e-5f);
  }
  __syncthreads();
  float mu = mu_s, r = r_s;
#pragma unroll
  for (int it = 0; it < 8; ++it) {
    int i = threadIdx.x + it * 256;
    out[b * S + i] = (t8[it] - mu) * r * g[i] + bb[i];
  }
}

extern "C" void kernel_launch(void* const* d_in, const int* in_sizes, int n_in,
                              void* d_out, int out_size, void* d_ws, size_t ws_size,
                              hipStream_t stream) {
  (void)in_sizes; (void)n_in; (void)out_size; (void)ws_size;
  const float* x    = (const float*)d_in[0];
  const float* Wq   = (const float*)d_in[1];
  const float* Wk   = (const float*)d_in[2];
  const float* Wv   = (const float*)d_in[3];
  const float* p2   = (const float*)d_in[4];
  const float* Wfc2 = (const float*)d_in[5];
  const float* bfc2 = (const float*)d_in[6];
  const float* g2   = (const float*)d_in[7];
  const float* b2   = (const float*)d_in[8];
  float* out = (float*)d_out;

  float* qkvp  = (float*)d_ws;                        // 2 * 3*32*2048 f32
  float* T     = qkvp + 2 * 3 * BATCH * S;            // 32*2048 f32
  float* Spart = T + BATCH * S;                       // 32*16 f32
  unsigned short* fchi = (unsigned short*)(Spart + BATCH * 16);  // 32*2048 u16
  unsigned short* fclo = fchi + BATCH * S;                       // 32*2048 u16
  float* yp    = (float*)(fclo + BATCH * S);          // 4 * 32*2048 f32

  k_qkv<<<768, 256, 0, stream>>>(x, Wq, Wk, Wv, qkvp);
  k_attn<<<512, 512, 0, stream>>>(qkvp, T, Spart);
  k_act<<<256, 256, 0, stream>>>(T, Spart, p2, fchi, fclo);
  k_fc<<<512, 256, 0, stream>>>(fchi, fclo, Wfc2, yp);
  k_ln<<<32, 256, 0, stream>>>(yp, bfc2, g2, b2, out);
}